// Round 6
// baseline (523.956 us; speedup 1.0000x reference)
//
#include <hip/hip_runtime.h>
#include <stdint.h>

#define NF 8192          // features per row
#define NR 8192          // rows
#define TPB 256          // threads per block
#define RPB 8            // rows per block
#define TGRID (NR / RPB) // 1024 blocks = exactly 4 resident per CU
#define KSEL 2867        // floor(0.35 * 8192)
#define CAND_EFF 1016    // cand[1016..1023] aliased as shp[] scalars
#define EQCAP 128
#define FCAP 64          // final-stage gather capacity (fin aliases hist[0..63])
#define NOPRED 0xFFFFFFFFu

typedef float    floatx4 __attribute__((ext_vector_type(4)));
typedef uint32_t uintx4  __attribute__((ext_vector_type(4)));

// order-preserving float -> uint mapping (ascending)
__device__ __forceinline__ uint32_t f2s(float f) {
    uint32_t u = __float_as_uint(f);
    return u ^ ((uint32_t)((int32_t)u >> 31) | 0x80000000u);
}

__global__ __launch_bounds__(TPB) void boost_k(const float* __restrict__ dc,
                                               float* __restrict__ boost) {
    const int i = blockIdx.x * TPB + threadIdx.x;
    const float target = (float)KSEL / (float)NF; // 0.3499755859375, exact in f32
    boost[i] = expf(1.5f * (target - dc[i]));
}

__device__ __forceinline__ bool kept2(uint32_t u, uint32_t T, uint32_t col,
                                      bool keepall, uint32_t need,
                                      const uint32_t* eq) {
    if (u > T) return true;
    if (u != T) return false;
    if (keepall) return true;
    for (uint32_t i = 0; i < need; ++i)
        if (eq[i] == col) return true;
    return false;
}

// wave 0: select over 1024 linear bins. Reads its 16 words, ZEROES them
// (clean-hist invariant, no extra barrier), suffix-scans, finds the bucket
// containing rank shp[1]. Composes shp[0] |= bin << shift.
__device__ __forceinline__ void selectN(uint32_t* hist, uint32_t* shp, int lane,
                                        int shift) {
    uintx4 q[4];
#pragma unroll
    for (int a = 0; a < 4; ++a) q[a] = ((uintx4*)hist)[4 * lane + a];
    const uintx4 z4 = {0u, 0u, 0u, 0u};
#pragma unroll
    for (int a = 0; a < 4; ++a) ((uintx4*)hist)[4 * lane + a] = z4; // zero-after-read
    uint32_t h[16];
#pragma unroll
    for (int a = 0; a < 4; ++a) {
        h[4 * a + 0] = q[a].x; h[4 * a + 1] = q[a].y;
        h[4 * a + 2] = q[a].z; h[4 * a + 3] = q[a].w;
    }
    uint32_t g = 0;
#pragma unroll
    for (int b = 0; b < 16; ++b) g += h[b];
    uint32_t inc = g;
#pragma unroll
    for (int off = 1; off < 64; off <<= 1) {
        const uint32_t o = __shfl_down(inc, off);
        if (lane + off < 64) inc += o;
    }
    const uint32_t kk = shp[1];
    const uint32_t above = inc - g; // keys in strictly higher bins
    if (above < kk && kk <= inc) {
        uint32_t c = above;
        const uint32_t oldp = shp[0];
#pragma unroll
        for (int b = 15; b >= 0; --b) {
            c += h[b];
            if (c >= kk) {
                shp[0] = oldp | ((uint32_t)(16 * lane + b) << shift);
                shp[1] = kk - (c - h[b]); // residual rank within bucket
                shp[2] = h[b];            // bucket population
                break;
            }
        }
    }
}

// wave 0: select over 256 bins x4 replicas (fallback passes). Zero-after-read.
__device__ __forceinline__ void select8(uint32_t* hist, uint32_t* shp, int lane,
                                        int shift) {
    uintx4 q[4];
#pragma unroll
    for (int a = 0; a < 4; ++a) q[a] = ((uintx4*)hist)[4 * lane + a];
    const uintx4 z4 = {0u, 0u, 0u, 0u};
#pragma unroll
    for (int a = 0; a < 4; ++a) ((uintx4*)hist)[4 * lane + a] = z4;
    uint32_t hh[4];
    uint32_t g = 0;
#pragma unroll
    for (int b = 0; b < 4; ++b) { // bin 4*lane+b = sum of its 4 replicas
        hh[b] = q[b].x + q[b].y + q[b].z + q[b].w;
        g += hh[b];
    }
    uint32_t inc = g;
#pragma unroll
    for (int off = 1; off < 64; off <<= 1) {
        const uint32_t o = __shfl_down(inc, off);
        if (lane + off < 64) inc += o;
    }
    const uint32_t kk = shp[1];
    const uint32_t above = inc - g;
    if (above < kk && kk <= inc) {
        uint32_t c = above;
        const uint32_t oldp = shp[0];
#pragma unroll
        for (int b = 3; b >= 0; --b) {
            c += hh[b];
            if (c >= kk) {
                shp[0] = oldp | ((uint32_t)(4 * lane + b) << shift);
                shp[1] = kk - (c - hh[b]);
                shp[2] = hh[b];
                break;
            }
        }
    }
}

// Row lives in LDS (su): one HBM read + one HBM write per element.
// Predictive compaction: during the stage scan, keys in the PREVIOUS row's
// pass-0 bucket are speculatively appended to cand. On hit (bucket unchanged,
// ~always for smooth data), the compact rescan is skipped. Radix 10+10, then
// a tiny gather (expected 1-2 keys) resolves the final 12 bits exactly.
// Full 8-bit fallback passes retained for adversarial data.
// LDS = 32768(su) + 4096(hist) + 4096(cand; shp tail, eq head) = 40960 B.
__global__ __launch_bounds__(TPB, 4) void topk_k(const float* __restrict__ x,
                                                 const float* __restrict__ boost,
                                                 float* __restrict__ out,
                                                 uint32_t* __restrict__ partials) {
    __shared__ __align__(16) uint32_t su[NF];     // x-bits of the current row
    __shared__ __align__(16) uint32_t hist[1024]; // 1024 bins / 256x4 / fin alias
    __shared__ __align__(16) uint32_t cand[1024]; // [0..1015] candidates

    uint32_t* const shp = &cand[1016]; // 0:prefix/T 1:rank 2:pop 3:cand 4:eq 5:fin
    uint32_t* const eq  = &cand[0];    // alias: used only after radix done
    uint32_t* const fin = &hist[0];    // alias: used only in tiny final stage

    const int t = threadIdx.x;
    const int lane = t & 63;
    const int wv = t >> 6;
    const int sub = t & 3;
    const uintx4 z4 = {0u, 0u, 0u, 0u};
    const floatx4* b4 = (const floatx4*)boost;

    ((uintx4*)hist)[t] = z4; // clean-hist invariant at row start

    uint32_t cnt4[4] = {0, 0, 0, 0}; // nibble-packed per-column pos counts
    uint32_t pred = NOPRED;          // predicted pass-0 bucket (uniform)

    for (int r = 0; r < RPB; ++r) {
        const int row = blockIdx.x * RPB + r;
        const floatx4* x4 = (const floatx4*)(x + (size_t)row * NF);

        if (t < 8) shp[t] = (t == 1) ? (uint32_t)KSEL : 0u;
        __syncthreads(); // prev-row su/eq readers done; shp init visible; hist clean

        // scan A: x -> su (one HBM read); hist0 (bits 31:22); predictive append
#pragma unroll
        for (int j = 0; j < 8; ++j) {
            const int idx = j * TPB + t;
            const floatx4 xv = __builtin_nontemporal_load(&x4[idx]);
            ((floatx4*)su)[idx] = xv;
            const floatx4 bv = b4[idx];
            uint32_t uu[4];
            uu[0] = f2s(xv.x * bv.x);
            uu[1] = f2s(xv.y * bv.y);
            uu[2] = f2s(xv.z * bv.z);
            uu[3] = f2s(xv.w * bv.w);
            atomicAdd(&hist[uu[0] >> 22], 1u);
            atomicAdd(&hist[uu[1] >> 22], 1u);
            atomicAdd(&hist[uu[2] >> 22], 1u);
            atomicAdd(&hist[uu[3] >> 22], 1u);
#pragma unroll
            for (int c = 0; c < 4; ++c) {
                const bool m = (uu[c] & 0xFFC00000u) == pred;
                const unsigned long long mk = __ballot(m);
                if (mk) { // wave-uniform
                    const int leader = __builtin_ctzll(mk);
                    uint32_t base = 0;
                    if (lane == leader)
                        base = atomicAdd(&shp[3], (uint32_t)__builtin_popcountll(mk));
                    base = __shfl(base, leader);
                    if (m) {
                        const uint32_t p = base + (uint32_t)__builtin_popcountll(
                                                      mk & ((1ull << lane) - 1ull));
                        if (p < CAND_EFF) cand[p] = uu[c]; // speculative: cap
                    }
                }
            }
        }
        __syncthreads();
        if (wv == 0) selectN(hist, shp, lane, 22);
        __syncthreads();

        const uint32_t pfx0 = shp[0];
        const uint32_t pop = shp[2];
        const bool uc = (pop <= (uint32_t)CAND_EFF);
        const bool hit = uc && (pfx0 == pred);
        pred = pfx0; // predict next row = this row's bucket

        if (!hit) { // miss: recompact with the actual bucket (or skip if !uc)
            if (t == 0) shp[3] = 0;
            __syncthreads();
            if (uc) {
#pragma unroll
                for (int j = 0; j < 8; ++j) {
                    const int idx = j * TPB + t;
                    const floatx4 xv = ((const floatx4*)su)[idx];
                    const floatx4 bv = b4[idx];
                    uint32_t uu[4];
                    uu[0] = f2s(xv.x * bv.x);
                    uu[1] = f2s(xv.y * bv.y);
                    uu[2] = f2s(xv.z * bv.z);
                    uu[3] = f2s(xv.w * bv.w);
#pragma unroll
                    for (int c = 0; c < 4; ++c) {
                        const bool m = (uu[c] & 0xFFC00000u) == pfx0;
                        const unsigned long long mk = __ballot(m);
                        if (mk) {
                            const int leader = __builtin_ctzll(mk);
                            uint32_t base = 0;
                            if (lane == leader)
                                base = atomicAdd(&shp[3],
                                                 (uint32_t)__builtin_popcountll(mk));
                            base = __shfl(base, leader);
                            if (m)
                                cand[base + (uint32_t)__builtin_popcountll(
                                                mk & ((1ull << lane) - 1ull))] = uu[c];
                        }
                    }
                }
            }
            __syncthreads();
        }

        // pass 1: bits 21:12 (1024 bins) over cand (or su when !uc)
        if (uc) {
            for (uint32_t i = t; i < pop; i += TPB)
                atomicAdd(&hist[(cand[i] >> 12) & 0x3FFu], 1u);
        } else {
#pragma unroll
            for (int j = 0; j < 8; ++j) {
                const int idx = j * TPB + t;
                const floatx4 xv = ((const floatx4*)su)[idx];
                const floatx4 bv = b4[idx];
                uint32_t uu[4];
                uu[0] = f2s(xv.x * bv.x);
                uu[1] = f2s(xv.y * bv.y);
                uu[2] = f2s(xv.z * bv.z);
                uu[3] = f2s(xv.w * bv.w);
#pragma unroll
                for (int c = 0; c < 4; ++c)
                    if ((uu[c] & 0xFFC00000u) == pfx0)
                        atomicAdd(&hist[(uu[c] >> 12) & 0x3FFu], 1u);
            }
        }
        __syncthreads();
        if (wv == 0) selectN(hist, shp, lane, 12);
        __syncthreads();

        const uint32_t pfx1 = shp[0];
        const uint32_t pop2 = shp[2];
        const bool tiny = uc && (pop2 <= (uint32_t)FCAP);

        if (tiny) {
            // gather the (expected 1-2) keys with the 20-bit prefix; exact pick
            for (uint32_t i = t; i < pop; i += TPB) {
                const uint32_t u = cand[i];
                const bool m = (u & 0xFFFFF000u) == pfx1;
                const unsigned long long mk = __ballot(m);
                if (mk) {
                    const int leader = __builtin_ctzll(mk);
                    uint32_t base = 0;
                    if (lane == leader)
                        base = atomicAdd(&shp[5], (uint32_t)__builtin_popcountll(mk));
                    base = __shfl(base, leader);
                    if (m) {
                        const uint32_t p = base + (uint32_t)__builtin_popcountll(
                                                      mk & ((1ull << lane) - 1ull));
                        if (p < FCAP) fin[p] = u;
                    }
                }
            }
            __syncthreads();
            if (t == 0) {
                const uint32_t mm = pop2;     // fully gathered (pop2 <= FCAP)
                const uint32_t kk = shp[1];   // residual rank, 1..mm
                for (uint32_t s = 0; s < kk; ++s) { // partial selection sort desc
                    uint32_t best = s, bvv = fin[s];
                    for (uint32_t i2 = s + 1; i2 < mm; ++i2) {
                        const uint32_t hv = fin[i2];
                        if (hv > bvv) { bvv = hv; best = i2; }
                    }
                    if (best != s) { fin[best] = fin[s]; fin[s] = bvv; }
                }
                const uint32_t Tv = fin[kk - 1];
                uint32_t gt = 0, meq2 = 0;
                for (uint32_t i2 = 0; i2 < mm; ++i2) {
                    const uint32_t hv = fin[i2];
                    gt += (hv > Tv) ? 1u : 0u;
                    meq2 += (hv == Tv) ? 1u : 0u;
                }
                shp[0] = Tv;
                shp[1] = kk - gt; // #ties to keep
                shp[2] = meq2;    // #(key == T)
            }
            __syncthreads();
            if (t < FCAP) fin[t] = 0; // restore clean-hist invariant
        } else {
            // fallback: pass 2 (bits 11:4) and pass 3 (bits 3:0), 256-bin x4
#pragma unroll
            for (int pass = 2; pass < 4; ++pass) {
                const int shift = (pass == 2) ? 4 : 0;
                const uint32_t himask = (pass == 2) ? 0xFFFFF000u : 0xFFFFFFF0u;
                const uint32_t bmask = (pass == 2) ? 0xFFu : 0xFu;
                const uint32_t prefix = shp[0];
                if (uc) {
                    for (uint32_t i = t; i < pop; i += TPB) {
                        const uint32_t u = cand[i];
                        if ((u & himask) == prefix)
                            atomicAdd(&hist[((u >> shift) & bmask) * 4 + sub], 1u);
                    }
                } else {
#pragma unroll
                    for (int j = 0; j < 8; ++j) {
                        const int idx = j * TPB + t;
                        const floatx4 xv = ((const floatx4*)su)[idx];
                        const floatx4 bv = b4[idx];
                        uint32_t uu[4];
                        uu[0] = f2s(xv.x * bv.x);
                        uu[1] = f2s(xv.y * bv.y);
                        uu[2] = f2s(xv.z * bv.z);
                        uu[3] = f2s(xv.w * bv.w);
#pragma unroll
                        for (int c = 0; c < 4; ++c)
                            if ((uu[c] & himask) == prefix)
                                atomicAdd(&hist[((uu[c] >> shift) & bmask) * 4 + sub],
                                          1u);
                    }
                }
                __syncthreads();
                if (wv == 0) select8(hist, shp, lane, shift);
                __syncthreads();
            }
        }
        // shp[0] = exact k-th largest key T; shp[1] = #ties to keep; shp[2] = #(==T)

        const uint32_t T = shp[0];
        const uint32_t need = shp[1];
        const bool keepall = (shp[2] == need);
        const uint32_t needc = (need < (uint32_t)EQCAP) ? need : (uint32_t)EQCAP;

        if (!keepall) { // rare: duplicate keys at the threshold; collect tie columns
#pragma unroll
            for (int j = 0; j < 8; ++j) {
                const int idx = j * TPB + t;
                const floatx4 xv = ((const floatx4*)su)[idx];
                const floatx4 bv = b4[idx];
                uint32_t uu[4];
                uu[0] = f2s(xv.x * bv.x);
                uu[1] = f2s(xv.y * bv.y);
                uu[2] = f2s(xv.z * bv.z);
                uu[3] = f2s(xv.w * bv.w);
#pragma unroll
                for (int c = 0; c < 4; ++c) {
                    if (uu[c] == T) {
                        const uint32_t p = atomicAdd(&shp[4], 1u);
                        if (p < EQCAP) eq[p] = (uint32_t)(4 * idx + c);
                    }
                }
            }
            __syncthreads();
            if (t == 0) { // keep lowest indices first (top_k stable tie-break)
                uint32_t m2 = shp[4];
                if (m2 > EQCAP) m2 = EQCAP;
                for (uint32_t i = 1; i < m2; ++i) {
                    const uint32_t key = eq[i];
                    int jj = (int)i - 1;
                    while (jj >= 0 && eq[jj] > key) { eq[jj + 1] = eq[jj]; --jj; }
                    eq[jj + 1] = key;
                }
            }
            __syncthreads();
        }

        // epilogue: read su, recompute keys, compare vs T, write out, count positives
        floatx4* o4 = (floatx4*)(out + (size_t)row * NF);
#pragma unroll
        for (int j = 0; j < 8; ++j) {
            const int idx = j * TPB + t;
            const floatx4 xv = ((const floatx4*)su)[idx];
            const floatx4 bv = b4[idx];
            const uint32_t u0 = f2s(xv.x * bv.x);
            const uint32_t u1 = f2s(xv.y * bv.y);
            const uint32_t u2 = f2s(xv.z * bv.z);
            const uint32_t u3 = f2s(xv.w * bv.w);
            const bool k0 = kept2(u0, T, (uint32_t)(4 * idx + 0), keepall, needc, eq);
            const bool k1 = kept2(u1, T, (uint32_t)(4 * idx + 1), keepall, needc, eq);
            const bool k2 = kept2(u2, T, (uint32_t)(4 * idx + 2), keepall, needc, eq);
            const bool k3 = kept2(u3, T, (uint32_t)(4 * idx + 3), keepall, needc, eq);
            floatx4 res;
            res.x = k0 ? xv.x : 0.0f;
            res.y = k1 ? xv.y : 0.0f;
            res.z = k2 ? xv.z : 0.0f;
            res.w = k3 ? xv.w : 0.0f;
            __builtin_nontemporal_store(res, &o4[idx]);
            uint32_t add = 0;
            add += (k0 && xv.x > 0.0f) ? (1u << (16 * (j & 1) + 0)) : 0u;
            add += (k1 && xv.y > 0.0f) ? (1u << (16 * (j & 1) + 4)) : 0u;
            add += (k2 && xv.z > 0.0f) ? (1u << (16 * (j & 1) + 8)) : 0u;
            add += (k3 && xv.w > 0.0f) ? (1u << (16 * (j & 1) + 12)) : 0u;
            cnt4[j >> 1] += add; // per-nibble max RPB=8 < 16, no overflow
        }
    }

    // nibble-packed per-block column counts -> workspace (coalesced, no atomics)
    {
        uint32_t* pb = partials + (size_t)blockIdx.x * (NF / 8);
#pragma unroll
        for (int jp = 0; jp < 4; ++jp) pb[jp * TPB + t] = cnt4[jp];
    }
}

// stage A: sum 16 nibble-packed block words -> byte-packed (max 16*8=128) — 64 blocks
__global__ __launch_bounds__(TPB) void redA_k(const uint32_t* __restrict__ partials,
                                              uint32_t* __restrict__ p2) {
    const int s = blockIdx.x; // 0..63
#pragma unroll
    for (int k2 = 0; k2 < 4; ++k2) {
        const int w = k2 * TPB + threadIdx.x; // 0..1023
        uint32_t a0 = 0, a1 = 0, a2 = 0, a3 = 0, a4 = 0, a5 = 0, a6 = 0, a7 = 0;
#pragma unroll
        for (int b = 0; b < 16; ++b) {
            const uint32_t p = partials[(size_t)(s * 16 + b) * 1024 + w];
            a0 += p & 0xFu;         a1 += (p >> 4) & 0xFu;
            a2 += (p >> 8) & 0xFu;  a3 += (p >> 12) & 0xFu;
            a4 += (p >> 16) & 0xFu; a5 += (p >> 20) & 0xFu;
            a6 += (p >> 24) & 0xFu; a7 += p >> 28;
        }
        p2[(size_t)s * 2048 + 2 * w]     = a0 | (a1 << 8) | (a2 << 16) | (a3 << 24);
        p2[(size_t)s * 2048 + 2 * w + 1] = a4 | (a5 << 8) | (a6 << 16) | (a7 << 24);
    }
}

// stage B: sum 64 byte-packed slices, unpack, finish EMA — 8 blocks
__global__ __launch_bounds__(TPB) void redB_k(const uint32_t* __restrict__ p2,
                                              const float* __restrict__ dc,
                                              float* __restrict__ dcout) {
    const int W = blockIdx.x * TPB + threadIdx.x; // 0..2047
    uint32_t s0 = 0, s1 = 0, s2 = 0, s3 = 0;
#pragma unroll 8
    for (int g = 0; g < 64; ++g) {
        const uint32_t p = p2[(size_t)g * 2048 + W];
        s0 += p & 0xFFu;
        s1 += (p >> 8) & 0xFFu;
        s2 += (p >> 16) & 0xFFu;
        s3 += p >> 24;
    }
    // word W = 2*w + h; w = jp*256+tt; columns 4*((2*jp+h)*256+tt) + 0..3
    const int w = W >> 1, h = W & 1;
    const int jp = w >> 8, tt = w & 255;
    const int idx4 = (2 * jp + h) * 256 + tt;
    const floatx4 d = ((const floatx4*)dc)[idx4];
    floatx4 rr;
    rr.x = 0.9f * d.x + 0.1f * (float)s0;
    rr.y = 0.9f * d.y + 0.1f * (float)s1;
    rr.z = 0.9f * d.z + 0.1f * (float)s2;
    rr.w = 0.9f * d.w + 0.1f * (float)s3;
    ((floatx4*)dcout)[idx4] = rr;
}

extern "C" void kernel_launch(void* const* d_in, const int* in_sizes, int n_in,
                              void* d_out, int out_size, void* d_ws, size_t ws_size,
                              hipStream_t stream) {
    (void)in_sizes; (void)n_in; (void)out_size; (void)ws_size;
    const float* x  = (const float*)d_in[0];
    const float* dc = (const float*)d_in[1];
    float* out   = (float*)d_out;
    float* dcout = out + (size_t)NR * NF;

    char* ws = (char*)d_ws;
    float*    boost    = (float*)ws;                    // 32 KB @ 0
    uint32_t* partials = (uint32_t*)(ws + (1u << 20));  // 4 MB  @ 1 MB (1024 x 1024 words)
    uint32_t* p2       = (uint32_t*)(ws + (9u << 20));  // 512 KB @ 9 MB (64 x 2048 words)

    boost_k<<<dim3(NF / TPB), dim3(TPB), 0, stream>>>(dc, boost);
    topk_k<<<dim3(TGRID), dim3(TPB), 0, stream>>>(x, boost, out, partials);
    redA_k<<<dim3(64), dim3(TPB), 0, stream>>>(partials, p2);
    redB_k<<<dim3(8), dim3(TPB), 0, stream>>>(p2, dc, dcout);
}